// Round 22
// baseline (210.419 us; speedup 1.0000x reference)
//
#include <hip/hip_runtime.h>
#include <hip/hip_bf16.h>

// ---------------------------------------------------------------------------
// GINE x2 + mean-pool + FC.
//   histB: per-tile LDS histogram of 512 dst-buckets -> bcnt
//   scanB: 1-block scan -> bstart/bcur
//   binA : 2048-edge tiles, LDS counting-sort into buckets, flush runs
//   binB : block=bucket: count -> deg/cursor, LDS sort, coalesced csr write,
//          fused conv1-aggregate + FUSED MLP1 (MFMA) -> h1b directly
//   agg2 : LEAN wave/node; quarter-uniform broadcast record loads (no shfl);
//          register accumulate -> p2b
//   mlp_mfma<64> -> h2b;  pool_fc.
// LESSONS: (r16) LDS f32 atomics at E*64 volume = 10x slower than register
// accumulate.  (r17) gather prefetch adds overhead.  (r19) fusing MFMA
// weights+LDS into the gather phase kills occupancy — keep gathers lean.
// [resubmit: round 21 hit the chronic dead container]
// ---------------------------------------------------------------------------

#define NBUCK 512
#define TILE_A 2048
#define PB_CAP 3584  // binB LDS record capacity (mean 3125 + 8 sigma)

typedef __attribute__((ext_vector_type(8))) short bf16x8;
typedef __attribute__((ext_vector_type(4))) float f32x4;
typedef __attribute__((ext_vector_type(4))) unsigned int u32x4;

__device__ __forceinline__ float bf2f(unsigned short u) {
  return __uint_as_float(((unsigned)u) << 16);
}
__device__ __forceinline__ unsigned short f2bf(float f) {
  __hip_bfloat16 hb = __float2bfloat16(f);
  return *reinterpret_cast<unsigned short*>(&hb);
}
__device__ __forceinline__ int bucket_lo(int b, int N) {
  return (int)(((long long)b * N + (NBUCK - 1)) >> 9);  // ceil(b*N/512)
}
// exact floor(d*512/N): float approx + integer fixup
__device__ __forceinline__ int bucket_of(int d, int N, float f512overN) {
  int b = (int)((float)d * f512overN);
  long long d512 = (long long)d << 9;
  if ((long long)(b + 1) * N <= d512) ++b;
  else if ((long long)b * N > d512) --b;
  return b;
}

__global__ __launch_bounds__(256) void histB_kernel(
    const int* __restrict__ dstIdx, int* __restrict__ bcnt, int E, int N,
    float f512overN) {
  __shared__ int cnt[NBUCK];
  int t = threadIdx.x;
  cnt[t] = 0;
  cnt[t + 256] = 0;
  __syncthreads();
  int e0 = blockIdx.x * TILE_A;
  int valid = min(TILE_A, E - e0);
#pragma unroll
  for (int k = 0; k < 8; ++k) {
    int idx = t + k * 256;
    if (idx < valid) {
      int d = dstIdx[e0 + idx];
      atomicAdd(&cnt[bucket_of(d, N, f512overN)], 1);
    }
  }
  __syncthreads();
  if (cnt[t]) atomicAdd(&bcnt[t], cnt[t]);
  if (cnt[t + 256]) atomicAdd(&bcnt[t + 256], cnt[t + 256]);
}

__global__ __launch_bounds__(256) void scanB_kernel(
    const int* __restrict__ bcnt, int* __restrict__ bstart,
    int* __restrict__ bcur, int E) {
  __shared__ int sd[256];
  int t = threadIdx.x;
  int base = t * 2;
  int v0 = bcnt[base];
  int v1 = bcnt[base + 1];
  int ts = v0 + v1;
  sd[t] = ts;
  __syncthreads();
  for (int off = 1; off < 256; off <<= 1) {
    int xv = (t >= off) ? sd[t - off] : 0;
    __syncthreads();
    sd[t] += xv;
    __syncthreads();
  }
  int excl = sd[t] - ts;
  bstart[base] = excl;
  bstart[base + 1] = excl + v0;
  bcur[base] = excl;
  bcur[base + 1] = excl + v0;
  if (t == 255) bstart[NBUCK] = E;
}

// passA: per-tile LDS counting sort into 512 buckets; flush contiguous runs.
__global__ __launch_bounds__(256) void binA_kernel(
    const int* __restrict__ srcIdx, const int* __restrict__ dstIdx,
    const float* __restrict__ ea, int* __restrict__ bcur,
    u32x4* __restrict__ binned, int E, int N, float f512overN) {
  __shared__ u32x4 recs[TILE_A];  // 32 KB
  __shared__ int cnt[NBUCK];
  __shared__ int off[NBUCK];
  int t = threadIdx.x;
  int e0 = blockIdx.x * TILE_A;
  int valid = min(TILE_A, E - e0);

  cnt[t] = 0;
  cnt[t + 256] = 0;
  __syncthreads();

  u32x4 rec[8];
  int bkt[8], slot[8];
#pragma unroll
  for (int k = 0; k < 8; ++k) {
    int idx = t + k * 256;
    bkt[k] = -1;
    if (idx < valid) {
      int e = e0 + idx;
      int d = dstIdx[e];
      int s = __builtin_nontemporal_load(&srcIdx[e]);
      f32x4 a = __builtin_nontemporal_load(
          reinterpret_cast<const f32x4*>(ea) + e);
      u32x4 v;
      v[0] = (unsigned)s;
      v[1] = (unsigned)f2bf(a[0]) | ((unsigned)f2bf(a[1]) << 16);
      v[2] = (unsigned)f2bf(a[2]) | ((unsigned)f2bf(a[3]) << 16);
      v[3] = (unsigned)d;
      rec[k] = v;
      int b = bucket_of(d, N, f512overN);
      bkt[k] = b;
      slot[k] = atomicAdd(&cnt[b], 1);
    }
  }
  __syncthreads();
  int c0 = cnt[t], c1 = cnt[t + 256];
  for (int o = 1; o < NBUCK; o <<= 1) {
    int v0 = (t >= o) ? cnt[t - o] : 0;
    int v1 = (t + 256 >= o) ? cnt[t + 256 - o] : 0;
    __syncthreads();
    cnt[t] += v0;
    cnt[t + 256] += v1;
    __syncthreads();
  }
  off[t] = cnt[t] - c0;
  off[t + 256] = cnt[t + 256] - c1;
  __syncthreads();
#pragma unroll
  for (int k = 0; k < 8; ++k)
    if (bkt[k] >= 0) recs[off[bkt[k]] + slot[k]] = rec[k];
  __syncthreads();
#pragma unroll
  for (int h = 0; h < 2; ++h) {
    int b = t + h * 256;
    int c = (h == 0) ? c0 : c1;
    if (c > 0) {
      int g = atomicAdd(&bcur[b], c);
      int o = off[b];
      for (int k = 0; k < c; ++k) binned[g + k] = recs[o + k];
    }
  }
}

// binB: block=bucket.  Count -> deg/cursor; LDS sort; coalesced csr write;
// fused conv1 aggregate; FUSED MLP1 via MFMA -> h1b.
__global__ __launch_bounds__(256) void binB_kernel(
    const u32x4* __restrict__ binned, const int* __restrict__ bstart,
    int* __restrict__ deg, int* __restrict__ cursor, int* __restrict__ gcur,
    u32x4* __restrict__ csr, const float* __restrict__ x,
    const float* __restrict__ We1, const float* __restrict__ be1,
    const float* __restrict__ W1a, const float* __restrict__ b1a,
    const float* __restrict__ W1b, const float* __restrict__ b1b,
    unsigned short* __restrict__ h1b, int N) {
  __shared__ u32x4 lrec[PB_CAP];  // 56 KB (aliased by pl/tlds after conv1)
  __shared__ int ldeg[256];
  __shared__ int lcur[256];
  int b = blockIdx.x;
  int t = threadIdx.x;
  int w = t >> 6, l = t & 63;
  int lr = l & 15, lq = l >> 4;
  int lo = bucket_lo(b, N);
  int lo1 = bucket_lo(b + 1, N);
  int nlocal = lo1 - lo;  // <= 197 < 256 by construction
  int rs = bstart[b];
  int re = bstart[b + 1];
  int count = re - rs;
  bf16x8 wa1[4], wb1[2][4];
#pragma unroll
  for (int c = 0; c < 4; ++c) {
    bf16x8 f;
#pragma unroll
    for (int r = 0; r < 8; ++r) {
      int row = lq * 8 + r;
      f[r] = (short)f2bf((row < 7) ? W1a[row * 64 + c * 16 + lr] : 0.f);
    }
    wa1[c] = f;
  }
#pragma unroll
  for (int ks = 0; ks < 2; ++ks)
#pragma unroll
    for (int c = 0; c < 4; ++c) {
      bf16x8 f;
#pragma unroll
      for (int r = 0; r < 8; ++r)
        f[r] = (short)f2bf(W1b[(ks * 32 + lq * 8 + r) * 64 + c * 16 + lr]);
      wb1[ks][c] = f;
    }
  float vba[4], vbb[4];
#pragma unroll
  for (int c = 0; c < 4; ++c) {
    vba[c] = b1a[c * 16 + lr];
    vbb[c] = b1b[c * 16 + lr];
  }
  float w1[28], b1[7];
#pragma unroll
  for (int i = 0; i < 28; ++i) w1[i] = We1[i];  // uniform -> SGPR
#pragma unroll
  for (int i = 0; i < 7; ++i) b1[i] = be1[i];

  ldeg[t] = 0;
  __syncthreads();
  for (int i = t; i < count; i += 256) {
    int d = (int)binned[rs + i][3];
    atomicAdd(&ldeg[d - lo], 1);
  }
  __syncthreads();
  int c = ldeg[t];
  lcur[t] = c;
  __syncthreads();
  for (int o = 1; o < 256; o <<= 1) {
    int v = (t >= o) ? lcur[t - o] : 0;
    __syncthreads();
    lcur[t] += v;
    __syncthreads();
  }
  int excl = lcur[t] - c;
  if (t < nlocal) {
    deg[lo + t] = c;
    cursor[lo + t] = rs + excl;  // coalesced row-start write
  }
  __syncthreads();
  lcur[t] = excl;
  __syncthreads();
  bool fits = (count <= PB_CAP);
  if (fits) {
    for (int i = t; i < count; i += 256) {
      u32x4 r = binned[rs + i];  // L2-hot second read
      int p = atomicAdd(&lcur[(int)r[3] - lo], 1);
      lrec[p] = r;
    }
    __syncthreads();
    for (int i = t; i < count; i += 256) csr[rs + i] = lrec[i];  // coalesced
  } else {
    if (t < nlocal) gcur[lo + t] = rs + excl;
    __threadfence();
    __syncthreads();
    for (int i = t; i < count; i += 256) {
      u32x4 r = binned[rs + i];
      int p = atomicAdd(&gcur[(int)r[3]], 1);
      csr[p] = r;
    }
    __threadfence();
    __syncthreads();
  }
  // ---- fused conv1 aggregate: node lo+t owns records [excl, excl+c) ----
  float acc[7];
#pragma unroll
  for (int ch = 0; ch < 7; ++ch) acc[ch] = 0.f;
  if (t < nlocal) {
    for (int i = excl; i < excl + c; ++i) {
      u32x4 r = fits ? lrec[i] : csr[rs + i];
      int s = (int)r[0];
      float a0 = __uint_as_float(r[1] << 16);
      float a1 = __uint_as_float(r[1] & 0xffff0000u);
      float a2 = __uint_as_float(r[2] << 16);
      float a3 = __uint_as_float(r[2] & 0xffff0000u);
      const float* xs = x + (size_t)s * 7;  // random 28B, L2-resident
#pragma unroll
      for (int ch = 0; ch < 7; ++ch) {
        float v = b1[ch] + a0 * w1[ch] + a1 * w1[7 + ch] + a2 * w1[14 + ch] +
                  a3 * w1[21 + ch] + xs[ch];
        acc[ch] += fmaxf(v, 0.f);
      }
    }
  }
  __syncthreads();  // all lrec reads done; safe to alias
  float* pl = (float*)lrec;  // bytes [0, 6400)
  unsigned short* tlds =
      (unsigned short*)((char*)lrec + 8192) + (size_t)w * (16 * 72);
  if (t < nlocal) {
    const float* xn = x + (size_t)(lo + t) * 7;
#pragma unroll
    for (int ch = 0; ch < 7; ++ch) pl[t * 8 + ch] = acc[ch] + xn[ch];
    pl[t * 8 + 7] = 0.f;
  }
  __syncthreads();
  // ---- fused MLP1 (MFMA, KIN=8) ----
  int ntile = (nlocal + 15) >> 4;
  for (int tile = w; tile < ntile; tile += 4) {
    int r0 = tile << 4;
    bf16x8 af0;
#pragma unroll
    for (int r = 0; r < 8; ++r) af0[r] = 0;
    if (lq == 0) {
      int row16 = r0 + lr;
      if (row16 < nlocal) {
        const float* pr = pl + row16 * 8;
#pragma unroll
        for (int r = 0; r < 8; ++r) af0[r] = (short)f2bf(pr[r]);
      }
    }
    f32x4 accA[4];
#pragma unroll
    for (int cc = 0; cc < 4; ++cc) {
      f32x4 a = {0.f, 0.f, 0.f, 0.f};
      accA[cc] = __builtin_amdgcn_mfma_f32_16x16x32_bf16(af0, wa1[cc], a, 0, 0, 0);
    }
#pragma unroll
    for (int cc = 0; cc < 4; ++cc)
#pragma unroll
      for (int r = 0; r < 4; ++r) {
        float v = fmaxf(accA[cc][r] + vba[cc], 0.f);
        tlds[(lq * 4 + r) * 72 + cc * 16 + lr] = f2bf(v);
      }
    bf16x8 tf0 = *(const bf16x8*)&tlds[lr * 72 + lq * 8];
    bf16x8 tf1 = *(const bf16x8*)&tlds[lr * 72 + 32 + lq * 8];
#pragma unroll
    for (int cc = 0; cc < 4; ++cc) {
      f32x4 a = {0.f, 0.f, 0.f, 0.f};
      a = __builtin_amdgcn_mfma_f32_16x16x32_bf16(tf0, wb1[0][cc], a, 0, 0, 0);
      a = __builtin_amdgcn_mfma_f32_16x16x32_bf16(tf1, wb1[1][cc], a, 0, 0, 0);
#pragma unroll
      for (int r = 0; r < 4; ++r) {
        int row16 = r0 + lq * 4 + r;
        if (row16 < nlocal) {
          float v = fmaxf(a[r] + vbb[cc], 0.f);
          h1b[(size_t)(lo + row16) * 64 + cc * 16 + lr] = f2bf(v);
        }
      }
    }
  }
}

// agg2: LEAN wave per node.  Each quarter (16 lanes) loads its record at a
// quarter-uniform address (HW broadcast, L1-hit) — no shfl.  Register
// accumulate; -> p2b.
__global__ __launch_bounds__(256) void agg2_kernel(
    const unsigned short* __restrict__ h1b, const u32x4* __restrict__ csr,
    const int* __restrict__ deg, const int* __restrict__ cursor,
    const float* __restrict__ We2, const float* __restrict__ be2,
    unsigned short* __restrict__ p2b, int N) {
  int w = threadIdx.x >> 6, j = threadIdx.x & 63;
  int q = j >> 4;  // record slot within quad 0..3
  int m = j & 15;  // channel quad
  float4 ew0 = *reinterpret_cast<const float4*>(&We2[0 * 64 + m * 4]);
  float4 ew1 = *reinterpret_cast<const float4*>(&We2[1 * 64 + m * 4]);
  float4 ew2 = *reinterpret_cast<const float4*>(&We2[2 * 64 + m * 4]);
  float4 ew3 = *reinterpret_cast<const float4*>(&We2[3 * 64 + m * 4]);
  float4 eb = *reinterpret_cast<const float4*>(&be2[m * 4]);
  int wid = blockIdx.x * 4 + w;
  int nw = gridDim.x * 4;
  for (int n = wid; n < N; n += nw) {
    int start = cursor[n];
    int end = start + deg[n];
    float acc0 = 0.f, acc1 = 0.f, acc2 = 0.f, acc3 = 0.f;
    for (int base = start; base < end; base += 4) {
      int rec = base + q;
      bool valid = rec < end;
      u32x4 u = {0u, 0u, 0u, 0u};
      if (valid) u = csr[rec];  // 16 lanes same addr -> broadcast, L1-hit
      int s = (int)u[0];
      ushort4 hv =
          *reinterpret_cast<const ushort4*>(&h1b[(size_t)s * 64 + m * 4]);
      float a0 = __uint_as_float(u[1] << 16);
      float a1 = __uint_as_float(u[1] & 0xffff0000u);
      float a2 = __uint_as_float(u[2] << 16);
      float a3 = __uint_as_float(u[2] & 0xffff0000u);
      float e0 = eb.x + a0 * ew0.x + a1 * ew1.x + a2 * ew2.x + a3 * ew3.x;
      float e1 = eb.y + a0 * ew0.y + a1 * ew1.y + a2 * ew2.y + a3 * ew3.y;
      float e2 = eb.z + a0 * ew0.z + a1 * ew1.z + a2 * ew2.z + a3 * ew3.z;
      float e3 = eb.w + a0 * ew0.w + a1 * ew1.w + a2 * ew2.w + a3 * ew3.w;
      if (valid) {
        acc0 += fmaxf(bf2f(hv.x) + e0, 0.f);
        acc1 += fmaxf(bf2f(hv.y) + e1, 0.f);
        acc2 += fmaxf(bf2f(hv.z) + e2, 0.f);
        acc3 += fmaxf(bf2f(hv.w) + e3, 0.f);
      }
    }
    acc0 += __shfl_xor(acc0, 16); acc0 += __shfl_xor(acc0, 32);
    acc1 += __shfl_xor(acc1, 16); acc1 += __shfl_xor(acc1, 32);
    acc2 += __shfl_xor(acc2, 16); acc2 += __shfl_xor(acc2, 32);
    acc3 += __shfl_xor(acc3, 16); acc3 += __shfl_xor(acc3, 32);
    ushort4 sv =
        *reinterpret_cast<const ushort4*>(&h1b[(size_t)n * 64 + m * 4]);
    if (q == 0) {
      ushort4 o;
      o.x = f2bf(acc0 + bf2f(sv.x));
      o.y = f2bf(acc1 + bf2f(sv.y));
      o.z = f2bf(acc2 + bf2f(sv.z));
      o.w = f2bf(acc3 + bf2f(sv.w));
      *reinterpret_cast<ushort4*>(&p2b[(size_t)n * 64 + m * 4]) = o;
    }
  }
}

// 2-layer MLP via MFMA 16x16x32 bf16 (KIN=64).  m89-verified layouts.
__global__ __launch_bounds__(256) void mlp2_mfma_kernel(
    const unsigned short* __restrict__ pin, const float* __restrict__ Wa,
    const float* __restrict__ ba, const float* __restrict__ Wb,
    const float* __restrict__ bb, unsigned short* __restrict__ hout, int N) {
  __shared__ unsigned short t_lds[4][16 * 72];
  int w = threadIdx.x >> 6, l = threadIdx.x & 63;
  int lr = l & 15, lq = l >> 4;
  bf16x8 wa[2][4], wb[2][4];
#pragma unroll
  for (int ks = 0; ks < 2; ++ks)
#pragma unroll
    for (int c = 0; c < 4; ++c) {
      bf16x8 f, g;
#pragma unroll
      for (int r = 0; r < 8; ++r) {
        int row = ks * 32 + lq * 8 + r;
        f[r] = (short)f2bf(Wa[row * 64 + c * 16 + lr]);
        g[r] = (short)f2bf(Wb[row * 64 + c * 16 + lr]);
      }
      wa[ks][c] = f;
      wb[ks][c] = g;
    }
  float vba[4], vbb[4];
#pragma unroll
  for (int c = 0; c < 4; ++c) {
    vba[c] = ba[c * 16 + lr];
    vbb[c] = bb[c * 16 + lr];
  }
  unsigned short* tl = t_lds[w];
  int ntiles = (N + 15) >> 4;
  for (int tile = blockIdx.x * 4 + w; tile < ntiles; tile += gridDim.x * 4) {
    int n0 = tile << 4;
    int arow = n0 + lr;
    bf16x8 af0, af1;
#pragma unroll
    for (int r = 0; r < 8; ++r) { af0[r] = 0; af1[r] = 0; }
    if (arow < N) {
      const unsigned short* pr = pin + (size_t)arow * 64 + lq * 8;
      af0 = *(const bf16x8*)(pr);
      af1 = *(const bf16x8*)(pr + 32);
    }
    f32x4 accA[4];
#pragma unroll
    for (int c = 0; c < 4; ++c) {
      f32x4 a = {0.f, 0.f, 0.f, 0.f};
      a = __builtin_amdgcn_mfma_f32_16x16x32_bf16(af0, wa[0][c], a, 0, 0, 0);
      a = __builtin_amdgcn_mfma_f32_16x16x32_bf16(af1, wa[1][c], a, 0, 0, 0);
      accA[c] = a;
    }
#pragma unroll
    for (int c = 0; c < 4; ++c)
#pragma unroll
      for (int r = 0; r < 4; ++r) {
        float v = fmaxf(accA[c][r] + vba[c], 0.f);
        tl[(lq * 4 + r) * 72 + c * 16 + lr] = f2bf(v);
      }
    bf16x8 tf0 = *(const bf16x8*)&tl[lr * 72 + lq * 8];
    bf16x8 tf1 = *(const bf16x8*)&tl[lr * 72 + 32 + lq * 8];
#pragma unroll
    for (int c = 0; c < 4; ++c) {
      f32x4 a = {0.f, 0.f, 0.f, 0.f};
      a = __builtin_amdgcn_mfma_f32_16x16x32_bf16(tf0, wb[0][c], a, 0, 0, 0);
      a = __builtin_amdgcn_mfma_f32_16x16x32_bf16(tf1, wb[1][c], a, 0, 0, 0);
#pragma unroll
      for (int r = 0; r < 4; ++r) {
        int row = n0 + lq * 4 + r;
        if (row < N) {
          float v = fmaxf(a[r] + vbb[c], 0.f);
          hout[(size_t)row * 64 + c * 16 + lr] = f2bf(v);
        }
      }
    }
  }
}

__global__ __launch_bounds__(64) void pool_fc_kernel(
    const unsigned short* __restrict__ h2b, const int* __restrict__ batch,
    const float* __restrict__ Wfc, const float* __restrict__ bfc,
    float* __restrict__ out, int N, int G) {
  int g = blockIdx.x;
  int j = threadIdx.x;
  int q = j >> 4;
  int m = j & 15;
  int lo = 0, hi = N;
  while (lo < hi) {
    int mid = (lo + hi) >> 1;
    if (batch[mid] < g) lo = mid + 1; else hi = mid;
  }
  int start = lo;
  lo = start; hi = N;
  while (lo < hi) {
    int mid = (lo + hi) >> 1;
    if (batch[mid] < g + 1) lo = mid + 1; else hi = mid;
  }
  int end = lo;
  int cnt = end - start;
  float s0 = 0.f, s1 = 0.f, s2 = 0.f, s3 = 0.f;
  int ngrp = (cnt + 3) >> 2;
  for (int it = 0; it < ngrp; ++it) {
    int r = start + it * 4 + q;
    if (r < end) {
      ushort4 hv =
          *reinterpret_cast<const ushort4*>(&h2b[(size_t)r * 64 + m * 4]);
      s0 += bf2f(hv.x);
      s1 += bf2f(hv.y);
      s2 += bf2f(hv.z);
      s3 += bf2f(hv.w);
    }
  }
  s0 += __shfl_xor(s0, 16); s0 += __shfl_xor(s0, 32);
  s1 += __shfl_xor(s1, 16); s1 += __shfl_xor(s1, 32);
  s2 += __shfl_xor(s2, 16); s2 += __shfl_xor(s2, 32);
  s3 += __shfl_xor(s3, 16); s3 += __shfl_xor(s3, 32);
  float inv = 1.f / fmaxf((float)cnt, 1.f);
  __shared__ float spool[64];
  if (q == 0) {
    spool[m * 4 + 0] = s0 * inv;
    spool[m * 4 + 1] = s1 * inv;
    spool[m * 4 + 2] = s2 * inv;
    spool[m * 4 + 3] = s3 * inv;
  }
  __syncthreads();
  if (j < 12) {
    float o = bfc[j];
#pragma unroll
    for (int k = 0; k < 64; ++k) o += spool[k] * Wfc[k * 12 + j];
    out[(size_t)g * 12 + j] = o;
  }
}

extern "C" void kernel_launch(void* const* d_in, const int* in_sizes, int n_in,
                              void* d_out, int out_size, void* d_ws,
                              size_t ws_size, hipStream_t stream) {
  const float* x   = (const float*)d_in[0];
  const float* ea  = (const float*)d_in[1];
  const float* We1 = (const float*)d_in[2];
  const float* be1 = (const float*)d_in[3];
  const float* We2 = (const float*)d_in[4];
  const float* be2 = (const float*)d_in[5];
  const float* W1a = (const float*)d_in[6];
  const float* b1a = (const float*)d_in[7];
  const float* W1b = (const float*)d_in[8];
  const float* b1b = (const float*)d_in[9];
  const float* W2a = (const float*)d_in[10];
  const float* b2a = (const float*)d_in[11];
  const float* W2b = (const float*)d_in[12];
  const float* b2b = (const float*)d_in[13];
  const float* Wfc = (const float*)d_in[14];
  const float* bfc = (const float*)d_in[15];
  const int* eidx  = (const int*)d_in[16];
  const int* batch = (const int*)d_in[17];

  int N = in_sizes[0] / 7;
  int E = in_sizes[1] / 4;
  int G = out_size / 12;
  const int* srcIdx = eidx;
  const int* dstIdx = eidx + E;

  char* ws = (char*)d_ws;
  int*   deg      = (int*)ws;             ws += (size_t)N * 4;
  int*   cursor   = (int*)ws;             ws += (size_t)N * 4;
  int*   gcur     = (int*)ws;             ws += (size_t)N * 4;
  int*   bcnt     = (int*)ws;             ws += NBUCK * 4;
  int*   bstart   = (int*)ws;             ws += (NBUCK + 1) * 4;
  int*   bcur     = (int*)ws;             ws += NBUCK * 4;
  ws = (char*)(((size_t)ws + 255) & ~(size_t)255);
  u32x4* csr      = (u32x4*)ws;           ws += (size_t)E * 16;
  u32x4* binned   = (u32x4*)ws;           ws += (size_t)E * 16;
  unsigned short* h1b = (unsigned short*)ws; ws += (size_t)N * 64 * 2;
  // p2b and h2b overlay binned (dead after binB): 12.8 + 12.8 = 25.6 MB = E*16
  unsigned short* p2b = (unsigned short*)binned;
  unsigned short* h2b = p2b + (size_t)N * 64;

  int ntiles = (N + 15) / 16;
  int mlpBlocks = (ntiles + 3) / 4;
  if (mlpBlocks > 1024) mlpBlocks = 1024;
  int ntilesA = (E + TILE_A - 1) / TILE_A;
  float f512overN = 512.0f / (float)N;

  hipMemsetAsync(bcnt, 0, NBUCK * 4, stream);
  histB_kernel<<<ntilesA, 256, 0, stream>>>(dstIdx, bcnt, E, N, f512overN);
  scanB_kernel<<<1, 256, 0, stream>>>(bcnt, bstart, bcur, E);
  binA_kernel<<<ntilesA, 256, 0, stream>>>(srcIdx, dstIdx, ea, bcur, binned,
                                           E, N, f512overN);
  binB_kernel<<<NBUCK, 256, 0, stream>>>(binned, bstart, deg, cursor, gcur,
                                         csr, x, We1, be1, W1a, b1a, W1b, b1b,
                                         h1b, N);
  agg2_kernel<<<2048, 256, 0, stream>>>(h1b, csr, deg, cursor, We2, be2, p2b,
                                        N);
  mlp2_mfma_kernel<<<mlpBlocks, 256, 0, stream>>>(p2b, W2a, b2a, W2b, b2b,
                                                  h2b, N);
  pool_fc_kernel<<<G, 64, 0, stream>>>(h2b, batch, Wfc, bfc, (float*)d_out, N,
                                       G);
}

// Round 25
// 169.558 us; speedup vs baseline: 1.2410x; 1.2410x over previous
//
#include <hip/hip_runtime.h>
#include <hip/hip_bf16.h>

// ---------------------------------------------------------------------------
// GINE x2 + mean-pool + FC.
//   binA : 2048-edge tiles, LDS counting-sort into 512 FIXED-CAP bucket
//          regions (binned[b*CAP..]); slots via atomicAdd(bcur[b]) from 0;
//          overflow (8-sigma, ~never) -> spill list.  NO hist, NO scan.
//   binB : block=bucket: count (main+spill) -> deg/cursor, LDS sort,
//          coalesced csr write (csr[b*CAP..]), fused conv1-aggregate +
//          FUSED MLP1 (MFMA) -> h1b directly
//   agg2 : LEAN wave/node quarter-parallel shfl gathers (r20 form) -> p2b
//   mlp_mfma<64> -> h2b;  pool_fc.
// LESSONS: (r16) LDS f32 atomics at E*64 volume = 10x slower than register
// accumulate.  (r17) gather prefetch adds overhead.  (r19) fusing MFMA
// weights+LDS into gather kills occupancy.  (r22) broadcast record loads
// are worse than shfl — shfl quarter-parallel is the plateau form for agg2.
// [resubmit x2: rounds 23/24 hit the chronic dead container]
// ---------------------------------------------------------------------------

#define NBUCK 512
#define TILE_A 2048
#define PB_CAP 3584   // per-bucket region capacity == binB LDS capacity
#define SPILL_CAP 8192

typedef __attribute__((ext_vector_type(8))) short bf16x8;
typedef __attribute__((ext_vector_type(4))) float f32x4;
typedef __attribute__((ext_vector_type(4))) unsigned int u32x4;

__device__ __forceinline__ float bf2f(unsigned short u) {
  return __uint_as_float(((unsigned)u) << 16);
}
__device__ __forceinline__ unsigned short f2bf(float f) {
  __hip_bfloat16 hb = __float2bfloat16(f);
  return *reinterpret_cast<unsigned short*>(&hb);
}
__device__ __forceinline__ int bucket_lo(int b, int N) {
  return (int)(((long long)b * N + (NBUCK - 1)) >> 9);  // ceil(b*N/512)
}
// exact floor(d*512/N): float approx + integer fixup
__device__ __forceinline__ int bucket_of(int d, int N, float f512overN) {
  int b = (int)((float)d * f512overN);
  long long d512 = (long long)d << 9;
  if ((long long)(b + 1) * N <= d512) ++b;
  else if ((long long)b * N > d512) --b;
  return b;
}

// binA: per-tile LDS counting sort into 512 buckets; flush runs into the
// bucket's fixed-cap region at a slot from atomicAdd(bcur[b]).
__global__ __launch_bounds__(256) void binA_kernel(
    const int* __restrict__ srcIdx, const int* __restrict__ dstIdx,
    const float* __restrict__ ea, int* __restrict__ bcur,
    u32x4* __restrict__ binned, u32x4* __restrict__ spill,
    int* __restrict__ spillCnt, int E, int N, float f512overN) {
  __shared__ u32x4 recs[TILE_A];  // 32 KB
  __shared__ int cnt[NBUCK];
  __shared__ int off[NBUCK];
  int t = threadIdx.x;
  int e0 = blockIdx.x * TILE_A;
  int valid = min(TILE_A, E - e0);

  cnt[t] = 0;
  cnt[t + 256] = 0;
  __syncthreads();

  u32x4 rec[8];
  int bkt[8], slot[8];
#pragma unroll
  for (int k = 0; k < 8; ++k) {
    int idx = t + k * 256;
    bkt[k] = -1;
    if (idx < valid) {
      int e = e0 + idx;
      int d = dstIdx[e];
      int s = __builtin_nontemporal_load(&srcIdx[e]);
      f32x4 a = __builtin_nontemporal_load(
          reinterpret_cast<const f32x4*>(ea) + e);
      u32x4 v;
      v[0] = (unsigned)s;
      v[1] = (unsigned)f2bf(a[0]) | ((unsigned)f2bf(a[1]) << 16);
      v[2] = (unsigned)f2bf(a[2]) | ((unsigned)f2bf(a[3]) << 16);
      v[3] = (unsigned)d;
      rec[k] = v;
      int b = bucket_of(d, N, f512overN);
      bkt[k] = b;
      slot[k] = atomicAdd(&cnt[b], 1);
    }
  }
  __syncthreads();
  int c0 = cnt[t], c1 = cnt[t + 256];
  for (int o = 1; o < NBUCK; o <<= 1) {
    int v0 = (t >= o) ? cnt[t - o] : 0;
    int v1 = (t + 256 >= o) ? cnt[t + 256 - o] : 0;
    __syncthreads();
    cnt[t] += v0;
    cnt[t + 256] += v1;
    __syncthreads();
  }
  off[t] = cnt[t] - c0;
  off[t + 256] = cnt[t + 256] - c1;
  __syncthreads();
#pragma unroll
  for (int k = 0; k < 8; ++k)
    if (bkt[k] >= 0) recs[off[bkt[k]] + slot[k]] = rec[k];
  __syncthreads();
#pragma unroll
  for (int h = 0; h < 2; ++h) {
    int b = t + h * 256;
    int c = (h == 0) ? c0 : c1;
    if (c > 0) {
      int g = atomicAdd(&bcur[b], c);
      int o = off[b];
      for (int k = 0; k < c; ++k) {
        int pos = g + k;
        if (pos < PB_CAP) {
          binned[(size_t)b * PB_CAP + pos] = recs[o + k];
        } else {  // ~never (8 sigma)
          int sp = atomicAdd(spillCnt, 1);
          if (sp < SPILL_CAP) spill[sp] = recs[o + k];
        }
      }
    }
  }
}

// binB: block=bucket.  Count (main+spill) -> deg/cursor; LDS sort; coalesced
// csr write; fused conv1 aggregate; FUSED MLP1 via MFMA -> h1b.
__global__ __launch_bounds__(256) void binB_kernel(
    const u32x4* __restrict__ binned, const int* __restrict__ bcur,
    const u32x4* __restrict__ spill, const int* __restrict__ spillCnt,
    int* __restrict__ deg, int* __restrict__ cursor, int* __restrict__ gcur,
    u32x4* __restrict__ csr, const float* __restrict__ x,
    const float* __restrict__ We1, const float* __restrict__ be1,
    const float* __restrict__ W1a, const float* __restrict__ b1a,
    const float* __restrict__ W1b, const float* __restrict__ b1b,
    unsigned short* __restrict__ h1b, int N, float f512overN) {
  __shared__ u32x4 lrec[PB_CAP];  // 56 KB (aliased by pl/tlds after conv1)
  __shared__ int ldeg[256];
  __shared__ int lcur[256];
  int b = blockIdx.x;
  int t = threadIdx.x;
  int w = t >> 6, l = t & 63;
  int lr = l & 15, lq = l >> 4;
  int lo = bucket_lo(b, N);
  int lo1 = bucket_lo(b + 1, N);
  int nlocal = lo1 - lo;  // <= 197 < 256 by construction
  int rs = b * PB_CAP;    // fixed-cap region start
  int mainCount = min(bcur[b], PB_CAP);
  int spillN = min(spillCnt[0], SPILL_CAP);
  bf16x8 wa1[4], wb1[2][4];
#pragma unroll
  for (int c = 0; c < 4; ++c) {
    bf16x8 f;
#pragma unroll
    for (int r = 0; r < 8; ++r) {
      int row = lq * 8 + r;
      f[r] = (short)f2bf((row < 7) ? W1a[row * 64 + c * 16 + lr] : 0.f);
    }
    wa1[c] = f;
  }
#pragma unroll
  for (int ks = 0; ks < 2; ++ks)
#pragma unroll
    for (int c = 0; c < 4; ++c) {
      bf16x8 f;
#pragma unroll
      for (int r = 0; r < 8; ++r)
        f[r] = (short)f2bf(W1b[(ks * 32 + lq * 8 + r) * 64 + c * 16 + lr]);
      wb1[ks][c] = f;
    }
  float vba[4], vbb[4];
#pragma unroll
  for (int c = 0; c < 4; ++c) {
    vba[c] = b1a[c * 16 + lr];
    vbb[c] = b1b[c * 16 + lr];
  }
  float w1[28], b1[7];
#pragma unroll
  for (int i = 0; i < 28; ++i) w1[i] = We1[i];  // uniform -> SGPR
#pragma unroll
  for (int i = 0; i < 7; ++i) b1[i] = be1[i];

  ldeg[t] = 0;
  __syncthreads();
  for (int i = t; i < mainCount; i += 256) {
    int d = (int)binned[rs + i][3];
    atomicAdd(&ldeg[d - lo], 1);
  }
  for (int i = t; i < spillN; i += 256) {  // ~never executes
    int d = (int)spill[i][3];
    if (bucket_of(d, N, f512overN) == b) atomicAdd(&ldeg[d - lo], 1);
  }
  __syncthreads();
  int c = ldeg[t];
  lcur[t] = c;
  __syncthreads();
  for (int o = 1; o < 256; o <<= 1) {
    int v = (t >= o) ? lcur[t - o] : 0;
    __syncthreads();
    lcur[t] += v;
    __syncthreads();
  }
  int total = lcur[255];  // inclusive sum = bucket record count
  int excl = lcur[t] - c;
  if (t < nlocal) {
    deg[lo + t] = c;
    cursor[lo + t] = rs + excl;  // coalesced row-start write
  }
  __syncthreads();
  lcur[t] = excl;
  __syncthreads();
  bool fits = (total <= PB_CAP);
  if (fits) {
    for (int i = t; i < mainCount; i += 256) {
      u32x4 r = binned[rs + i];  // L2-hot second read
      int p = atomicAdd(&lcur[(int)r[3] - lo], 1);
      lrec[p] = r;
    }
    for (int i = t; i < spillN; i += 256) {  // ~never
      u32x4 r = spill[i];
      if (bucket_of((int)r[3], N, f512overN) == b) {
        int p = atomicAdd(&lcur[(int)r[3] - lo], 1);
        lrec[p] = r;
      }
    }
    __syncthreads();
    for (int i = t; i < total; i += 256) csr[rs + i] = lrec[i];  // coalesced
  } else {  // ~never (needs >PB_CAP records in one bucket)
    if (t < nlocal) gcur[lo + t] = rs + excl;
    __threadfence();
    __syncthreads();
    for (int i = t; i < mainCount; i += 256) {
      u32x4 r = binned[rs + i];
      int p = atomicAdd(&gcur[(int)r[3]], 1);
      csr[p] = r;
    }
    for (int i = t; i < spillN; i += 256) {
      u32x4 r = spill[i];
      if (bucket_of((int)r[3], N, f512overN) == b) {
        int p = atomicAdd(&gcur[(int)r[3]], 1);
        csr[p] = r;
      }
    }
    __threadfence();
    __syncthreads();
  }
  // ---- fused conv1 aggregate: node lo+t owns records [excl, excl+c) ----
  float acc[7];
#pragma unroll
  for (int ch = 0; ch < 7; ++ch) acc[ch] = 0.f;
  if (t < nlocal) {
    for (int i = excl; i < excl + c; ++i) {
      u32x4 r = fits ? lrec[i] : csr[rs + i];
      int s = (int)r[0];
      float a0 = __uint_as_float(r[1] << 16);
      float a1 = __uint_as_float(r[1] & 0xffff0000u);
      float a2 = __uint_as_float(r[2] << 16);
      float a3 = __uint_as_float(r[2] & 0xffff0000u);
      const float* xs = x + (size_t)s * 7;  // random 28B, L2-resident
#pragma unroll
      for (int ch = 0; ch < 7; ++ch) {
        float v = b1[ch] + a0 * w1[ch] + a1 * w1[7 + ch] + a2 * w1[14 + ch] +
                  a3 * w1[21 + ch] + xs[ch];
        acc[ch] += fmaxf(v, 0.f);
      }
    }
  }
  __syncthreads();  // all lrec reads done; safe to alias
  float* pl = (float*)lrec;  // bytes [0, 6400)
  unsigned short* tlds =
      (unsigned short*)((char*)lrec + 8192) + (size_t)w * (16 * 72);
  if (t < nlocal) {
    const float* xn = x + (size_t)(lo + t) * 7;
#pragma unroll
    for (int ch = 0; ch < 7; ++ch) pl[t * 8 + ch] = acc[ch] + xn[ch];
    pl[t * 8 + 7] = 0.f;
  }
  __syncthreads();
  // ---- fused MLP1 (MFMA, KIN=8) ----
  int ntile = (nlocal + 15) >> 4;
  for (int tile = w; tile < ntile; tile += 4) {
    int r0 = tile << 4;
    bf16x8 af0;
#pragma unroll
    for (int r = 0; r < 8; ++r) af0[r] = 0;
    if (lq == 0) {
      int row16 = r0 + lr;
      if (row16 < nlocal) {
        const float* pr = pl + row16 * 8;
#pragma unroll
        for (int r = 0; r < 8; ++r) af0[r] = (short)f2bf(pr[r]);
      }
    }
    f32x4 accA[4];
#pragma unroll
    for (int cc = 0; cc < 4; ++cc) {
      f32x4 a = {0.f, 0.f, 0.f, 0.f};
      accA[cc] = __builtin_amdgcn_mfma_f32_16x16x32_bf16(af0, wa1[cc], a, 0, 0, 0);
    }
#pragma unroll
    for (int cc = 0; cc < 4; ++cc)
#pragma unroll
      for (int r = 0; r < 4; ++r) {
        float v = fmaxf(accA[cc][r] + vba[cc], 0.f);
        tlds[(lq * 4 + r) * 72 + cc * 16 + lr] = f2bf(v);
      }
    bf16x8 tf0 = *(const bf16x8*)&tlds[lr * 72 + lq * 8];
    bf16x8 tf1 = *(const bf16x8*)&tlds[lr * 72 + 32 + lq * 8];
#pragma unroll
    for (int cc = 0; cc < 4; ++cc) {
      f32x4 a = {0.f, 0.f, 0.f, 0.f};
      a = __builtin_amdgcn_mfma_f32_16x16x32_bf16(tf0, wb1[0][cc], a, 0, 0, 0);
      a = __builtin_amdgcn_mfma_f32_16x16x32_bf16(tf1, wb1[1][cc], a, 0, 0, 0);
#pragma unroll
      for (int r = 0; r < 4; ++r) {
        int row16 = r0 + lq * 4 + r;
        if (row16 < nlocal) {
          float v = fmaxf(a[r] + vbb[cc], 0.f);
          h1b[(size_t)(lo + row16) * 64 + cc * 16 + lr] = f2bf(v);
        }
      }
    }
  }
}

// agg2: LEAN wave per node, quarter-parallel shfl gathers (r20 plateau form).
__global__ __launch_bounds__(256) void agg2_kernel(
    const unsigned short* __restrict__ h1b, const u32x4* __restrict__ csr,
    const int* __restrict__ deg, const int* __restrict__ cursor,
    const float* __restrict__ We2, const float* __restrict__ be2,
    unsigned short* __restrict__ p2b, int N) {
  int w = threadIdx.x >> 6, j = threadIdx.x & 63;
  int q = j >> 4;  // edge slot 0..3
  int m = j & 15;  // channel quad
  float4 ew0 = *reinterpret_cast<const float4*>(&We2[0 * 64 + m * 4]);
  float4 ew1 = *reinterpret_cast<const float4*>(&We2[1 * 64 + m * 4]);
  float4 ew2 = *reinterpret_cast<const float4*>(&We2[2 * 64 + m * 4]);
  float4 ew3 = *reinterpret_cast<const float4*>(&We2[3 * 64 + m * 4]);
  float4 eb = *reinterpret_cast<const float4*>(&be2[m * 4]);
  int wid = blockIdx.x * 4 + w;
  int nw = gridDim.x * 4;
  for (int n = wid; n < N; n += nw) {
    int start = cursor[n];
    int end = start + deg[n];
    float acc0 = 0.f, acc1 = 0.f, acc2 = 0.f, acc3 = 0.f;
    for (int base = start; base < end; base += 64) {
      int cnt = min(64, end - base);
      int sl = 0;
      int ax = 0, ay = 0;
      if (base + j < end) {
        u32x4 u = csr[base + j];  // coalesced 16B
        sl = (int)u[0];
        ax = (int)u[1];
        ay = (int)u[2];
      }
      int ngrp = (cnt + 3) >> 2;
      for (int it = 0; it < ngrp; ++it) {  // wave-uniform trip count
        int lane = it * 4 + q;
        int s = __shfl(sl, lane);
        unsigned uax = (unsigned)__shfl(ax, lane);
        unsigned uay = (unsigned)__shfl(ay, lane);
        ushort4 hv =
            *reinterpret_cast<const ushort4*>(&h1b[(size_t)s * 64 + m * 4]);
        float a0 = __uint_as_float(uax << 16);
        float a1 = __uint_as_float(uax & 0xffff0000u);
        float a2 = __uint_as_float(uay << 16);
        float a3 = __uint_as_float(uay & 0xffff0000u);
        float e0 = eb.x + a0 * ew0.x + a1 * ew1.x + a2 * ew2.x + a3 * ew3.x;
        float e1 = eb.y + a0 * ew0.y + a1 * ew1.y + a2 * ew2.y + a3 * ew3.y;
        float e2 = eb.z + a0 * ew0.z + a1 * ew1.z + a2 * ew2.z + a3 * ew3.z;
        float e3 = eb.w + a0 * ew0.w + a1 * ew1.w + a2 * ew2.w + a3 * ew3.w;
        if (lane < cnt) {
          acc0 += fmaxf(bf2f(hv.x) + e0, 0.f);
          acc1 += fmaxf(bf2f(hv.y) + e1, 0.f);
          acc2 += fmaxf(bf2f(hv.z) + e2, 0.f);
          acc3 += fmaxf(bf2f(hv.w) + e3, 0.f);
        }
      }
    }
    acc0 += __shfl_xor(acc0, 16); acc0 += __shfl_xor(acc0, 32);
    acc1 += __shfl_xor(acc1, 16); acc1 += __shfl_xor(acc1, 32);
    acc2 += __shfl_xor(acc2, 16); acc2 += __shfl_xor(acc2, 32);
    acc3 += __shfl_xor(acc3, 16); acc3 += __shfl_xor(acc3, 32);
    ushort4 sv =
        *reinterpret_cast<const ushort4*>(&h1b[(size_t)n * 64 + m * 4]);
    if (q == 0) {
      ushort4 o;
      o.x = f2bf(acc0 + bf2f(sv.x));
      o.y = f2bf(acc1 + bf2f(sv.y));
      o.z = f2bf(acc2 + bf2f(sv.z));
      o.w = f2bf(acc3 + bf2f(sv.w));
      *reinterpret_cast<ushort4*>(&p2b[(size_t)n * 64 + m * 4]) = o;
    }
  }
}

// 2-layer MLP via MFMA 16x16x32 bf16 (KIN=64).  m89-verified layouts.
__global__ __launch_bounds__(256) void mlp2_mfma_kernel(
    const unsigned short* __restrict__ pin, const float* __restrict__ Wa,
    const float* __restrict__ ba, const float* __restrict__ Wb,
    const float* __restrict__ bb, unsigned short* __restrict__ hout, int N) {
  __shared__ unsigned short t_lds[4][16 * 72];
  int w = threadIdx.x >> 6, l = threadIdx.x & 63;
  int lr = l & 15, lq = l >> 4;
  bf16x8 wa[2][4], wb[2][4];
#pragma unroll
  for (int ks = 0; ks < 2; ++ks)
#pragma unroll
    for (int c = 0; c < 4; ++c) {
      bf16x8 f, g;
#pragma unroll
      for (int r = 0; r < 8; ++r) {
        int row = ks * 32 + lq * 8 + r;
        f[r] = (short)f2bf(Wa[row * 64 + c * 16 + lr]);
        g[r] = (short)f2bf(Wb[row * 64 + c * 16 + lr]);
      }
      wa[ks][c] = f;
      wb[ks][c] = g;
    }
  float vba[4], vbb[4];
#pragma unroll
  for (int c = 0; c < 4; ++c) {
    vba[c] = ba[c * 16 + lr];
    vbb[c] = bb[c * 16 + lr];
  }
  unsigned short* tl = t_lds[w];
  int ntiles = (N + 15) >> 4;
  for (int tile = blockIdx.x * 4 + w; tile < ntiles; tile += gridDim.x * 4) {
    int n0 = tile << 4;
    int arow = n0 + lr;
    bf16x8 af0, af1;
#pragma unroll
    for (int r = 0; r < 8; ++r) { af0[r] = 0; af1[r] = 0; }
    if (arow < N) {
      const unsigned short* pr = pin + (size_t)arow * 64 + lq * 8;
      af0 = *(const bf16x8*)(pr);
      af1 = *(const bf16x8*)(pr + 32);
    }
    f32x4 accA[4];
#pragma unroll
    for (int c = 0; c < 4; ++c) {
      f32x4 a = {0.f, 0.f, 0.f, 0.f};
      a = __builtin_amdgcn_mfma_f32_16x16x32_bf16(af0, wa[0][c], a, 0, 0, 0);
      a = __builtin_amdgcn_mfma_f32_16x16x32_bf16(af1, wa[1][c], a, 0, 0, 0);
      accA[c] = a;
    }
#pragma unroll
    for (int c = 0; c < 4; ++c)
#pragma unroll
      for (int r = 0; r < 4; ++r) {
        float v = fmaxf(accA[c][r] + vba[c], 0.f);
        tl[(lq * 4 + r) * 72 + c * 16 + lr] = f2bf(v);
      }
    bf16x8 tf0 = *(const bf16x8*)&tl[lr * 72 + lq * 8];
    bf16x8 tf1 = *(const bf16x8*)&tl[lr * 72 + 32 + lq * 8];
#pragma unroll
    for (int c = 0; c < 4; ++c) {
      f32x4 a = {0.f, 0.f, 0.f, 0.f};
      a = __builtin_amdgcn_mfma_f32_16x16x32_bf16(tf0, wb[0][c], a, 0, 0, 0);
      a = __builtin_amdgcn_mfma_f32_16x16x32_bf16(tf1, wb[1][c], a, 0, 0, 0);
#pragma unroll
      for (int r = 0; r < 4; ++r) {
        int row = n0 + lq * 4 + r;
        if (row < N) {
          float v = fmaxf(a[r] + vbb[c], 0.f);
          hout[(size_t)row * 64 + c * 16 + lr] = f2bf(v);
        }
      }
    }
  }
}

__global__ __launch_bounds__(64) void pool_fc_kernel(
    const unsigned short* __restrict__ h2b, const int* __restrict__ batch,
    const float* __restrict__ Wfc, const float* __restrict__ bfc,
    float* __restrict__ out, int N, int G) {
  int g = blockIdx.x;
  int j = threadIdx.x;
  int q = j >> 4;
  int m = j & 15;
  int lo = 0, hi = N;
  while (lo < hi) {
    int mid = (lo + hi) >> 1;
    if (batch[mid] < g) lo = mid + 1; else hi = mid;
  }
  int start = lo;
  lo = start; hi = N;
  while (lo < hi) {
    int mid = (lo + hi) >> 1;
    if (batch[mid] < g + 1) lo = mid + 1; else hi = mid;
  }
  int end = lo;
  int cnt = end - start;
  float s0 = 0.f, s1 = 0.f, s2 = 0.f, s3 = 0.f;
  int ngrp = (cnt + 3) >> 2;
  for (int it = 0; it < ngrp; ++it) {
    int r = start + it * 4 + q;
    if (r < end) {
      ushort4 hv =
          *reinterpret_cast<const ushort4*>(&h2b[(size_t)r * 64 + m * 4]);
      s0 += bf2f(hv.x);
      s1 += bf2f(hv.y);
      s2 += bf2f(hv.z);
      s3 += bf2f(hv.w);
    }
  }
  s0 += __shfl_xor(s0, 16); s0 += __shfl_xor(s0, 32);
  s1 += __shfl_xor(s1, 16); s1 += __shfl_xor(s1, 32);
  s2 += __shfl_xor(s2, 16); s2 += __shfl_xor(s2, 32);
  s3 += __shfl_xor(s3, 16); s3 += __shfl_xor(s3, 32);
  float inv = 1.f / fmaxf((float)cnt, 1.f);
  __shared__ float spool[64];
  if (q == 0) {
    spool[m * 4 + 0] = s0 * inv;
    spool[m * 4 + 1] = s1 * inv;
    spool[m * 4 + 2] = s2 * inv;
    spool[m * 4 + 3] = s3 * inv;
  }
  __syncthreads();
  if (j < 12) {
    float o = bfc[j];
#pragma unroll
    for (int k = 0; k < 64; ++k) o += spool[k] * Wfc[k * 12 + j];
    out[(size_t)g * 12 + j] = o;
  }
}

extern "C" void kernel_launch(void* const* d_in, const int* in_sizes, int n_in,
                              void* d_out, int out_size, void* d_ws,
                              size_t ws_size, hipStream_t stream) {
  const float* x   = (const float*)d_in[0];
  const float* ea  = (const float*)d_in[1];
  const float* We1 = (const float*)d_in[2];
  const float* be1 = (const float*)d_in[3];
  const float* We2 = (const float*)d_in[4];
  const float* be2 = (const float*)d_in[5];
  const float* W1a = (const float*)d_in[6];
  const float* b1a = (const float*)d_in[7];
  const float* W1b = (const float*)d_in[8];
  const float* b1b = (const float*)d_in[9];
  const float* W2a = (const float*)d_in[10];
  const float* b2a = (const float*)d_in[11];
  const float* W2b = (const float*)d_in[12];
  const float* b2b = (const float*)d_in[13];
  const float* Wfc = (const float*)d_in[14];
  const float* bfc = (const float*)d_in[15];
  const int* eidx  = (const int*)d_in[16];
  const int* batch = (const int*)d_in[17];

  int N = in_sizes[0] / 7;
  int E = in_sizes[1] / 4;
  int G = out_size / 12;
  const int* srcIdx = eidx;
  const int* dstIdx = eidx + E;

  char* ws = (char*)d_ws;
  int*   deg      = (int*)ws;             ws += (size_t)N * 4;
  int*   cursor   = (int*)ws;             ws += (size_t)N * 4;
  int*   gcur     = (int*)ws;             ws += (size_t)N * 4;
  int*   bcur     = (int*)ws;             ws += NBUCK * 4;
  int*   spillCnt = (int*)ws;             ws += 256;  // padded
  ws = (char*)(((size_t)ws + 255) & ~(size_t)255);
  u32x4* csr      = (u32x4*)ws;           ws += (size_t)NBUCK * PB_CAP * 16;
  u32x4* binned   = (u32x4*)ws;           ws += (size_t)NBUCK * PB_CAP * 16;
  u32x4* spill    = (u32x4*)ws;           ws += (size_t)SPILL_CAP * 16;
  unsigned short* h1b = (unsigned short*)ws; ws += (size_t)N * 64 * 2;
  // p2b and h2b overlay binned (dead after binB): 25.6 MB <= 29.4 MB region
  unsigned short* p2b = (unsigned short*)binned;
  unsigned short* h2b = p2b + (size_t)N * 64;
  // total ~ 1.2 + 29.4 + 29.4 + 0.13 + 12.8 ~= 73 MB

  int ntiles = (N + 15) / 16;
  int mlpBlocks = (ntiles + 3) / 4;
  if (mlpBlocks > 1024) mlpBlocks = 1024;
  int ntilesA = (E + TILE_A - 1) / TILE_A;
  float f512overN = 512.0f / (float)N;

  hipMemsetAsync(bcur, 0, NBUCK * 4 + 256, stream);
  binA_kernel<<<ntilesA, 256, 0, stream>>>(srcIdx, dstIdx, ea, bcur, binned,
                                           spill, spillCnt, E, N, f512overN);
  binB_kernel<<<NBUCK, 256, 0, stream>>>(binned, bcur, spill, spillCnt, deg,
                                         cursor, gcur, csr, x, We1, be1, W1a,
                                         b1a, W1b, b1b, h1b, N, f512overN);
  agg2_kernel<<<2048, 256, 0, stream>>>(h1b, csr, deg, cursor, We2, be2, p2b,
                                        N);
  mlp2_mfma_kernel<<<mlpBlocks, 256, 0, stream>>>(p2b, W2a, b2a, W2b, b2b,
                                                  h2b, N);
  pool_fc_kernel<<<G, 64, 0, stream>>>(h2b, batch, Wfc, bfc, (float*)d_out, N,
                                       G);
}

// Round 26
// 169.251 us; speedup vs baseline: 1.2432x; 1.0018x over previous
//
#include <hip/hip_runtime.h>
#include <hip/hip_bf16.h>

// ---------------------------------------------------------------------------
// GINE x2 + mean-pool + FC.   (best: 169.6us @ r25; this round: agg2 grid 2x)
//   binA : 2048-edge tiles, LDS counting-sort into 512 FIXED-CAP bucket
//          regions; slots via atomicAdd(bcur[b]); overflow -> spill (~never).
//   binB : block=bucket: count -> deg/cursor, LDS sort, coalesced csr write,
//          fused conv1-aggregate + FUSED MLP1 (MFMA) -> h1b
//   agg2 : LEAN wave/node quarter-parallel shfl gathers -> p2b  (grid 4096)
//   mlp_mfma<64> -> h2b;  pool_fc.
// LESSONS: (r16) LDS f32 atomics at E*64 volume = 10x slower than register
// accumulate.  (r17) gather prefetch adds overhead.  (r19) fusing MFMA
// weights+LDS into gather kills occupancy.  (r22) broadcast record loads
// are worse than shfl — shfl quarter-parallel is the plateau form for agg2.
// ---------------------------------------------------------------------------

#define NBUCK 512
#define TILE_A 2048
#define PB_CAP 3584   // per-bucket region capacity == binB LDS capacity
#define SPILL_CAP 8192

typedef __attribute__((ext_vector_type(8))) short bf16x8;
typedef __attribute__((ext_vector_type(4))) float f32x4;
typedef __attribute__((ext_vector_type(4))) unsigned int u32x4;

__device__ __forceinline__ float bf2f(unsigned short u) {
  return __uint_as_float(((unsigned)u) << 16);
}
__device__ __forceinline__ unsigned short f2bf(float f) {
  __hip_bfloat16 hb = __float2bfloat16(f);
  return *reinterpret_cast<unsigned short*>(&hb);
}
__device__ __forceinline__ int bucket_lo(int b, int N) {
  return (int)(((long long)b * N + (NBUCK - 1)) >> 9);  // ceil(b*N/512)
}
// exact floor(d*512/N): float approx + integer fixup
__device__ __forceinline__ int bucket_of(int d, int N, float f512overN) {
  int b = (int)((float)d * f512overN);
  long long d512 = (long long)d << 9;
  if ((long long)(b + 1) * N <= d512) ++b;
  else if ((long long)b * N > d512) --b;
  return b;
}

// binA: per-tile LDS counting sort into 512 buckets; flush runs into the
// bucket's fixed-cap region at a slot from atomicAdd(bcur[b]).
__global__ __launch_bounds__(256) void binA_kernel(
    const int* __restrict__ srcIdx, const int* __restrict__ dstIdx,
    const float* __restrict__ ea, int* __restrict__ bcur,
    u32x4* __restrict__ binned, u32x4* __restrict__ spill,
    int* __restrict__ spillCnt, int E, int N, float f512overN) {
  __shared__ u32x4 recs[TILE_A];  // 32 KB
  __shared__ int cnt[NBUCK];
  __shared__ int off[NBUCK];
  int t = threadIdx.x;
  int e0 = blockIdx.x * TILE_A;
  int valid = min(TILE_A, E - e0);

  cnt[t] = 0;
  cnt[t + 256] = 0;
  __syncthreads();

  u32x4 rec[8];
  int bkt[8], slot[8];
#pragma unroll
  for (int k = 0; k < 8; ++k) {
    int idx = t + k * 256;
    bkt[k] = -1;
    if (idx < valid) {
      int e = e0 + idx;
      int d = dstIdx[e];
      int s = __builtin_nontemporal_load(&srcIdx[e]);
      f32x4 a = __builtin_nontemporal_load(
          reinterpret_cast<const f32x4*>(ea) + e);
      u32x4 v;
      v[0] = (unsigned)s;
      v[1] = (unsigned)f2bf(a[0]) | ((unsigned)f2bf(a[1]) << 16);
      v[2] = (unsigned)f2bf(a[2]) | ((unsigned)f2bf(a[3]) << 16);
      v[3] = (unsigned)d;
      rec[k] = v;
      int b = bucket_of(d, N, f512overN);
      bkt[k] = b;
      slot[k] = atomicAdd(&cnt[b], 1);
    }
  }
  __syncthreads();
  int c0 = cnt[t], c1 = cnt[t + 256];
  for (int o = 1; o < NBUCK; o <<= 1) {
    int v0 = (t >= o) ? cnt[t - o] : 0;
    int v1 = (t + 256 >= o) ? cnt[t + 256 - o] : 0;
    __syncthreads();
    cnt[t] += v0;
    cnt[t + 256] += v1;
    __syncthreads();
  }
  off[t] = cnt[t] - c0;
  off[t + 256] = cnt[t + 256] - c1;
  __syncthreads();
#pragma unroll
  for (int k = 0; k < 8; ++k)
    if (bkt[k] >= 0) recs[off[bkt[k]] + slot[k]] = rec[k];
  __syncthreads();
#pragma unroll
  for (int h = 0; h < 2; ++h) {
    int b = t + h * 256;
    int c = (h == 0) ? c0 : c1;
    if (c > 0) {
      int g = atomicAdd(&bcur[b], c);
      int o = off[b];
      for (int k = 0; k < c; ++k) {
        int pos = g + k;
        if (pos < PB_CAP) {
          binned[(size_t)b * PB_CAP + pos] = recs[o + k];
        } else {  // ~never (8 sigma)
          int sp = atomicAdd(spillCnt, 1);
          if (sp < SPILL_CAP) spill[sp] = recs[o + k];
        }
      }
    }
  }
}

// binB: block=bucket.  Count (main+spill) -> deg/cursor; LDS sort; coalesced
// csr write; fused conv1 aggregate; FUSED MLP1 via MFMA -> h1b.
__global__ __launch_bounds__(256) void binB_kernel(
    const u32x4* __restrict__ binned, const int* __restrict__ bcur,
    const u32x4* __restrict__ spill, const int* __restrict__ spillCnt,
    int* __restrict__ deg, int* __restrict__ cursor, int* __restrict__ gcur,
    u32x4* __restrict__ csr, const float* __restrict__ x,
    const float* __restrict__ We1, const float* __restrict__ be1,
    const float* __restrict__ W1a, const float* __restrict__ b1a,
    const float* __restrict__ W1b, const float* __restrict__ b1b,
    unsigned short* __restrict__ h1b, int N, float f512overN) {
  __shared__ u32x4 lrec[PB_CAP];  // 56 KB (aliased by pl/tlds after conv1)
  __shared__ int ldeg[256];
  __shared__ int lcur[256];
  int b = blockIdx.x;
  int t = threadIdx.x;
  int w = t >> 6, l = t & 63;
  int lr = l & 15, lq = l >> 4;
  int lo = bucket_lo(b, N);
  int lo1 = bucket_lo(b + 1, N);
  int nlocal = lo1 - lo;  // <= 197 < 256 by construction
  int rs = b * PB_CAP;    // fixed-cap region start
  int mainCount = min(bcur[b], PB_CAP);
  int spillN = min(spillCnt[0], SPILL_CAP);
  bf16x8 wa1[4], wb1[2][4];
#pragma unroll
  for (int c = 0; c < 4; ++c) {
    bf16x8 f;
#pragma unroll
    for (int r = 0; r < 8; ++r) {
      int row = lq * 8 + r;
      f[r] = (short)f2bf((row < 7) ? W1a[row * 64 + c * 16 + lr] : 0.f);
    }
    wa1[c] = f;
  }
#pragma unroll
  for (int ks = 0; ks < 2; ++ks)
#pragma unroll
    for (int c = 0; c < 4; ++c) {
      bf16x8 f;
#pragma unroll
      for (int r = 0; r < 8; ++r)
        f[r] = (short)f2bf(W1b[(ks * 32 + lq * 8 + r) * 64 + c * 16 + lr]);
      wb1[ks][c] = f;
    }
  float vba[4], vbb[4];
#pragma unroll
  for (int c = 0; c < 4; ++c) {
    vba[c] = b1a[c * 16 + lr];
    vbb[c] = b1b[c * 16 + lr];
  }
  float w1[28], b1[7];
#pragma unroll
  for (int i = 0; i < 28; ++i) w1[i] = We1[i];  // uniform -> SGPR
#pragma unroll
  for (int i = 0; i < 7; ++i) b1[i] = be1[i];

  ldeg[t] = 0;
  __syncthreads();
  for (int i = t; i < mainCount; i += 256) {
    int d = (int)binned[rs + i][3];
    atomicAdd(&ldeg[d - lo], 1);
  }
  for (int i = t; i < spillN; i += 256) {  // ~never executes
    int d = (int)spill[i][3];
    if (bucket_of(d, N, f512overN) == b) atomicAdd(&ldeg[d - lo], 1);
  }
  __syncthreads();
  int c = ldeg[t];
  lcur[t] = c;
  __syncthreads();
  for (int o = 1; o < 256; o <<= 1) {
    int v = (t >= o) ? lcur[t - o] : 0;
    __syncthreads();
    lcur[t] += v;
    __syncthreads();
  }
  int total = lcur[255];  // inclusive sum = bucket record count
  int excl = lcur[t] - c;
  if (t < nlocal) {
    deg[lo + t] = c;
    cursor[lo + t] = rs + excl;  // coalesced row-start write
  }
  __syncthreads();
  lcur[t] = excl;
  __syncthreads();
  bool fits = (total <= PB_CAP);
  if (fits) {
    for (int i = t; i < mainCount; i += 256) {
      u32x4 r = binned[rs + i];  // L2-hot second read
      int p = atomicAdd(&lcur[(int)r[3] - lo], 1);
      lrec[p] = r;
    }
    for (int i = t; i < spillN; i += 256) {  // ~never
      u32x4 r = spill[i];
      if (bucket_of((int)r[3], N, f512overN) == b) {
        int p = atomicAdd(&lcur[(int)r[3] - lo], 1);
        lrec[p] = r;
      }
    }
    __syncthreads();
    for (int i = t; i < total; i += 256) csr[rs + i] = lrec[i];  // coalesced
  } else {  // ~never (needs >PB_CAP records in one bucket)
    if (t < nlocal) gcur[lo + t] = rs + excl;
    __threadfence();
    __syncthreads();
    for (int i = t; i < mainCount; i += 256) {
      u32x4 r = binned[rs + i];
      int p = atomicAdd(&gcur[(int)r[3]], 1);
      csr[p] = r;
    }
    for (int i = t; i < spillN; i += 256) {
      u32x4 r = spill[i];
      if (bucket_of((int)r[3], N, f512overN) == b) {
        int p = atomicAdd(&gcur[(int)r[3]], 1);
        csr[p] = r;
      }
    }
    __threadfence();
    __syncthreads();
  }
  // ---- fused conv1 aggregate: node lo+t owns records [excl, excl+c) ----
  float acc[7];
#pragma unroll
  for (int ch = 0; ch < 7; ++ch) acc[ch] = 0.f;
  if (t < nlocal) {
    for (int i = excl; i < excl + c; ++i) {
      u32x4 r = fits ? lrec[i] : csr[rs + i];
      int s = (int)r[0];
      float a0 = __uint_as_float(r[1] << 16);
      float a1 = __uint_as_float(r[1] & 0xffff0000u);
      float a2 = __uint_as_float(r[2] << 16);
      float a3 = __uint_as_float(r[2] & 0xffff0000u);
      const float* xs = x + (size_t)s * 7;  // random 28B, L2-resident
#pragma unroll
      for (int ch = 0; ch < 7; ++ch) {
        float v = b1[ch] + a0 * w1[ch] + a1 * w1[7 + ch] + a2 * w1[14 + ch] +
                  a3 * w1[21 + ch] + xs[ch];
        acc[ch] += fmaxf(v, 0.f);
      }
    }
  }
  __syncthreads();  // all lrec reads done; safe to alias
  float* pl = (float*)lrec;  // bytes [0, 6400)
  unsigned short* tlds =
      (unsigned short*)((char*)lrec + 8192) + (size_t)w * (16 * 72);
  if (t < nlocal) {
    const float* xn = x + (size_t)(lo + t) * 7;
#pragma unroll
    for (int ch = 0; ch < 7; ++ch) pl[t * 8 + ch] = acc[ch] + xn[ch];
    pl[t * 8 + 7] = 0.f;
  }
  __syncthreads();
  // ---- fused MLP1 (MFMA, KIN=8) ----
  int ntile = (nlocal + 15) >> 4;
  for (int tile = w; tile < ntile; tile += 4) {
    int r0 = tile << 4;
    bf16x8 af0;
#pragma unroll
    for (int r = 0; r < 8; ++r) af0[r] = 0;
    if (lq == 0) {
      int row16 = r0 + lr;
      if (row16 < nlocal) {
        const float* pr = pl + row16 * 8;
#pragma unroll
        for (int r = 0; r < 8; ++r) af0[r] = (short)f2bf(pr[r]);
      }
    }
    f32x4 accA[4];
#pragma unroll
    for (int cc = 0; cc < 4; ++cc) {
      f32x4 a = {0.f, 0.f, 0.f, 0.f};
      accA[cc] = __builtin_amdgcn_mfma_f32_16x16x32_bf16(af0, wa1[cc], a, 0, 0, 0);
    }
#pragma unroll
    for (int cc = 0; cc < 4; ++cc)
#pragma unroll
      for (int r = 0; r < 4; ++r) {
        float v = fmaxf(accA[cc][r] + vba[cc], 0.f);
        tlds[(lq * 4 + r) * 72 + cc * 16 + lr] = f2bf(v);
      }
    bf16x8 tf0 = *(const bf16x8*)&tlds[lr * 72 + lq * 8];
    bf16x8 tf1 = *(const bf16x8*)&tlds[lr * 72 + 32 + lq * 8];
#pragma unroll
    for (int cc = 0; cc < 4; ++cc) {
      f32x4 a = {0.f, 0.f, 0.f, 0.f};
      a = __builtin_amdgcn_mfma_f32_16x16x32_bf16(tf0, wb1[0][cc], a, 0, 0, 0);
      a = __builtin_amdgcn_mfma_f32_16x16x32_bf16(tf1, wb1[1][cc], a, 0, 0, 0);
#pragma unroll
      for (int r = 0; r < 4; ++r) {
        int row16 = r0 + lq * 4 + r;
        if (row16 < nlocal) {
          float v = fmaxf(a[r] + vbb[cc], 0.f);
          h1b[(size_t)(lo + row16) * 64 + cc * 16 + lr] = f2bf(v);
        }
      }
    }
  }
}

// agg2: LEAN wave per node, quarter-parallel shfl gathers (plateau form).
__global__ __launch_bounds__(256) void agg2_kernel(
    const unsigned short* __restrict__ h1b, const u32x4* __restrict__ csr,
    const int* __restrict__ deg, const int* __restrict__ cursor,
    const float* __restrict__ We2, const float* __restrict__ be2,
    unsigned short* __restrict__ p2b, int N) {
  int w = threadIdx.x >> 6, j = threadIdx.x & 63;
  int q = j >> 4;  // edge slot 0..3
  int m = j & 15;  // channel quad
  float4 ew0 = *reinterpret_cast<const float4*>(&We2[0 * 64 + m * 4]);
  float4 ew1 = *reinterpret_cast<const float4*>(&We2[1 * 64 + m * 4]);
  float4 ew2 = *reinterpret_cast<const float4*>(&We2[2 * 64 + m * 4]);
  float4 ew3 = *reinterpret_cast<const float4*>(&We2[3 * 64 + m * 4]);
  float4 eb = *reinterpret_cast<const float4*>(&be2[m * 4]);
  int wid = blockIdx.x * 4 + w;
  int nw = gridDim.x * 4;
  for (int n = wid; n < N; n += nw) {
    int start = cursor[n];
    int end = start + deg[n];
    float acc0 = 0.f, acc1 = 0.f, acc2 = 0.f, acc3 = 0.f;
    for (int base = start; base < end; base += 64) {
      int cnt = min(64, end - base);
      int sl = 0;
      int ax = 0, ay = 0;
      if (base + j < end) {
        u32x4 u = csr[base + j];  // coalesced 16B
        sl = (int)u[0];
        ax = (int)u[1];
        ay = (int)u[2];
      }
      int ngrp = (cnt + 3) >> 2;
      for (int it = 0; it < ngrp; ++it) {  // wave-uniform trip count
        int lane = it * 4 + q;
        int s = __shfl(sl, lane);
        unsigned uax = (unsigned)__shfl(ax, lane);
        unsigned uay = (unsigned)__shfl(ay, lane);
        ushort4 hv =
            *reinterpret_cast<const ushort4*>(&h1b[(size_t)s * 64 + m * 4]);
        float a0 = __uint_as_float(uax << 16);
        float a1 = __uint_as_float(uax & 0xffff0000u);
        float a2 = __uint_as_float(uay << 16);
        float a3 = __uint_as_float(uay & 0xffff0000u);
        float e0 = eb.x + a0 * ew0.x + a1 * ew1.x + a2 * ew2.x + a3 * ew3.x;
        float e1 = eb.y + a0 * ew0.y + a1 * ew1.y + a2 * ew2.y + a3 * ew3.y;
        float e2 = eb.z + a0 * ew0.z + a1 * ew1.z + a2 * ew2.z + a3 * ew3.z;
        float e3 = eb.w + a0 * ew0.w + a1 * ew1.w + a2 * ew2.w + a3 * ew3.w;
        if (lane < cnt) {
          acc0 += fmaxf(bf2f(hv.x) + e0, 0.f);
          acc1 += fmaxf(bf2f(hv.y) + e1, 0.f);
          acc2 += fmaxf(bf2f(hv.z) + e2, 0.f);
          acc3 += fmaxf(bf2f(hv.w) + e3, 0.f);
        }
      }
    }
    acc0 += __shfl_xor(acc0, 16); acc0 += __shfl_xor(acc0, 32);
    acc1 += __shfl_xor(acc1, 16); acc1 += __shfl_xor(acc1, 32);
    acc2 += __shfl_xor(acc2, 16); acc2 += __shfl_xor(acc2, 32);
    acc3 += __shfl_xor(acc3, 16); acc3 += __shfl_xor(acc3, 32);
    ushort4 sv =
        *reinterpret_cast<const ushort4*>(&h1b[(size_t)n * 64 + m * 4]);
    if (q == 0) {
      ushort4 o;
      o.x = f2bf(acc0 + bf2f(sv.x));
      o.y = f2bf(acc1 + bf2f(sv.y));
      o.z = f2bf(acc2 + bf2f(sv.z));
      o.w = f2bf(acc3 + bf2f(sv.w));
      *reinterpret_cast<ushort4*>(&p2b[(size_t)n * 64 + m * 4]) = o;
    }
  }
}

// 2-layer MLP via MFMA 16x16x32 bf16 (KIN=64).  m89-verified layouts.
__global__ __launch_bounds__(256) void mlp2_mfma_kernel(
    const unsigned short* __restrict__ pin, const float* __restrict__ Wa,
    const float* __restrict__ ba, const float* __restrict__ Wb,
    const float* __restrict__ bb, unsigned short* __restrict__ hout, int N) {
  __shared__ unsigned short t_lds[4][16 * 72];
  int w = threadIdx.x >> 6, l = threadIdx.x & 63;
  int lr = l & 15, lq = l >> 4;
  bf16x8 wa[2][4], wb[2][4];
#pragma unroll
  for (int ks = 0; ks < 2; ++ks)
#pragma unroll
    for (int c = 0; c < 4; ++c) {
      bf16x8 f, g;
#pragma unroll
      for (int r = 0; r < 8; ++r) {
        int row = ks * 32 + lq * 8 + r;
        f[r] = (short)f2bf(Wa[row * 64 + c * 16 + lr]);
        g[r] = (short)f2bf(Wb[row * 64 + c * 16 + lr]);
      }
      wa[ks][c] = f;
      wb[ks][c] = g;
    }
  float vba[4], vbb[4];
#pragma unroll
  for (int c = 0; c < 4; ++c) {
    vba[c] = ba[c * 16 + lr];
    vbb[c] = bb[c * 16 + lr];
  }
  unsigned short* tl = t_lds[w];
  int ntiles = (N + 15) >> 4;
  for (int tile = blockIdx.x * 4 + w; tile < ntiles; tile += gridDim.x * 4) {
    int n0 = tile << 4;
    int arow = n0 + lr;
    bf16x8 af0, af1;
#pragma unroll
    for (int r = 0; r < 8; ++r) { af0[r] = 0; af1[r] = 0; }
    if (arow < N) {
      const unsigned short* pr = pin + (size_t)arow * 64 + lq * 8;
      af0 = *(const bf16x8*)(pr);
      af1 = *(const bf16x8*)(pr + 32);
    }
    f32x4 accA[4];
#pragma unroll
    for (int c = 0; c < 4; ++c) {
      f32x4 a = {0.f, 0.f, 0.f, 0.f};
      a = __builtin_amdgcn_mfma_f32_16x16x32_bf16(af0, wa[0][c], a, 0, 0, 0);
      a = __builtin_amdgcn_mfma_f32_16x16x32_bf16(af1, wa[1][c], a, 0, 0, 0);
      accA[c] = a;
    }
#pragma unroll
    for (int c = 0; c < 4; ++c)
#pragma unroll
      for (int r = 0; r < 4; ++r) {
        float v = fmaxf(accA[c][r] + vba[c], 0.f);
        tl[(lq * 4 + r) * 72 + c * 16 + lr] = f2bf(v);
      }
    bf16x8 tf0 = *(const bf16x8*)&tl[lr * 72 + lq * 8];
    bf16x8 tf1 = *(const bf16x8*)&tl[lr * 72 + 32 + lq * 8];
#pragma unroll
    for (int c = 0; c < 4; ++c) {
      f32x4 a = {0.f, 0.f, 0.f, 0.f};
      a = __builtin_amdgcn_mfma_f32_16x16x32_bf16(tf0, wb[0][c], a, 0, 0, 0);
      a = __builtin_amdgcn_mfma_f32_16x16x32_bf16(tf1, wb[1][c], a, 0, 0, 0);
#pragma unroll
      for (int r = 0; r < 4; ++r) {
        int row = n0 + lq * 4 + r;
        if (row < N) {
          float v = fmaxf(a[r] + vbb[c], 0.f);
          hout[(size_t)row * 64 + c * 16 + lr] = f2bf(v);
        }
      }
    }
  }
}

__global__ __launch_bounds__(64) void pool_fc_kernel(
    const unsigned short* __restrict__ h2b, const int* __restrict__ batch,
    const float* __restrict__ Wfc, const float* __restrict__ bfc,
    float* __restrict__ out, int N, int G) {
  int g = blockIdx.x;
  int j = threadIdx.x;
  int q = j >> 4;
  int m = j & 15;
  int lo = 0, hi = N;
  while (lo < hi) {
    int mid = (lo + hi) >> 1;
    if (batch[mid] < g) lo = mid + 1; else hi = mid;
  }
  int start = lo;
  lo = start; hi = N;
  while (lo < hi) {
    int mid = (lo + hi) >> 1;
    if (batch[mid] < g + 1) lo = mid + 1; else hi = mid;
  }
  int end = lo;
  int cnt = end - start;
  float s0 = 0.f, s1 = 0.f, s2 = 0.f, s3 = 0.f;
  int ngrp = (cnt + 3) >> 2;
  for (int it = 0; it < ngrp; ++it) {
    int r = start + it * 4 + q;
    if (r < end) {
      ushort4 hv =
          *reinterpret_cast<const ushort4*>(&h2b[(size_t)r * 64 + m * 4]);
      s0 += bf2f(hv.x);
      s1 += bf2f(hv.y);
      s2 += bf2f(hv.z);
      s3 += bf2f(hv.w);
    }
  }
  s0 += __shfl_xor(s0, 16); s0 += __shfl_xor(s0, 32);
  s1 += __shfl_xor(s1, 16); s1 += __shfl_xor(s1, 32);
  s2 += __shfl_xor(s2, 16); s2 += __shfl_xor(s2, 32);
  s3 += __shfl_xor(s3, 16); s3 += __shfl_xor(s3, 32);
  float inv = 1.f / fmaxf((float)cnt, 1.f);
  __shared__ float spool[64];
  if (q == 0) {
    spool[m * 4 + 0] = s0 * inv;
    spool[m * 4 + 1] = s1 * inv;
    spool[m * 4 + 2] = s2 * inv;
    spool[m * 4 + 3] = s3 * inv;
  }
  __syncthreads();
  if (j < 12) {
    float o = bfc[j];
#pragma unroll
    for (int k = 0; k < 64; ++k) o += spool[k] * Wfc[k * 12 + j];
    out[(size_t)g * 12 + j] = o;
  }
}

extern "C" void kernel_launch(void* const* d_in, const int* in_sizes, int n_in,
                              void* d_out, int out_size, void* d_ws,
                              size_t ws_size, hipStream_t stream) {
  const float* x   = (const float*)d_in[0];
  const float* ea  = (const float*)d_in[1];
  const float* We1 = (const float*)d_in[2];
  const float* be1 = (const float*)d_in[3];
  const float* We2 = (const float*)d_in[4];
  const float* be2 = (const float*)d_in[5];
  const float* W1a = (const float*)d_in[6];
  const float* b1a = (const float*)d_in[7];
  const float* W1b = (const float*)d_in[8];
  const float* b1b = (const float*)d_in[9];
  const float* W2a = (const float*)d_in[10];
  const float* b2a = (const float*)d_in[11];
  const float* W2b = (const float*)d_in[12];
  const float* b2b = (const float*)d_in[13];
  const float* Wfc = (const float*)d_in[14];
  const float* bfc = (const float*)d_in[15];
  const int* eidx  = (const int*)d_in[16];
  const int* batch = (const int*)d_in[17];

  int N = in_sizes[0] / 7;
  int E = in_sizes[1] / 4;
  int G = out_size / 12;
  const int* srcIdx = eidx;
  const int* dstIdx = eidx + E;

  char* ws = (char*)d_ws;
  int*   deg      = (int*)ws;             ws += (size_t)N * 4;
  int*   cursor   = (int*)ws;             ws += (size_t)N * 4;
  int*   gcur     = (int*)ws;             ws += (size_t)N * 4;
  int*   bcur     = (int*)ws;             ws += NBUCK * 4;
  int*   spillCnt = (int*)ws;             ws += 256;  // padded
  ws = (char*)(((size_t)ws + 255) & ~(size_t)255);
  u32x4* csr      = (u32x4*)ws;           ws += (size_t)NBUCK * PB_CAP * 16;
  u32x4* binned   = (u32x4*)ws;           ws += (size_t)NBUCK * PB_CAP * 16;
  u32x4* spill    = (u32x4*)ws;           ws += (size_t)SPILL_CAP * 16;
  unsigned short* h1b = (unsigned short*)ws; ws += (size_t)N * 64 * 2;
  // p2b and h2b overlay binned (dead after binB): 25.6 MB <= 29.4 MB region
  unsigned short* p2b = (unsigned short*)binned;
  unsigned short* h2b = p2b + (size_t)N * 64;
  // total ~ 1.2 + 29.4 + 29.4 + 0.13 + 12.8 ~= 73 MB

  int ntiles = (N + 15) / 16;
  int mlpBlocks = (ntiles + 3) / 4;
  if (mlpBlocks > 1024) mlpBlocks = 1024;
  int ntilesA = (E + TILE_A - 1) / TILE_A;
  float f512overN = 512.0f / (float)N;

  hipMemsetAsync(bcur, 0, NBUCK * 4 + 256, stream);
  binA_kernel<<<ntilesA, 256, 0, stream>>>(srcIdx, dstIdx, ea, bcur, binned,
                                           spill, spillCnt, E, N, f512overN);
  binB_kernel<<<NBUCK, 256, 0, stream>>>(binned, bcur, spill, spillCnt, deg,
                                         cursor, gcur, csr, x, We1, be1, W1a,
                                         b1a, W1b, b1b, h1b, N, f512overN);
  agg2_kernel<<<4096, 256, 0, stream>>>(h1b, csr, deg, cursor, We2, be2, p2b,
                                        N);
  mlp2_mfma_kernel<<<mlpBlocks, 256, 0, stream>>>(p2b, W2a, b2a, W2b, b2b,
                                                  h2b, N);
  pool_fc_kernel<<<G, 64, 0, stream>>>(h2b, batch, Wfc, bfc, (float*)d_out, N,
                                       G);
}